// Round 5
// baseline (4147.862 us; speedup 1.0000x reference)
//
#include <hip/hip_runtime.h>

#define S_LEN 4096
#define LCH   16
#define CED   64
#define CHD   128
#define WED   256
#define WHD   256
#define TAGV  64

typedef _Float16 hf;
typedef _Float16 hf2 __attribute__((ext_vector_type(2)));

union PK2 { int i; hf2 h; };

__device__ __forceinline__ float dot2i(int a, int b, float acc) {
  PK2 ua, ub; ua.i = a; ub.i = b;
#if __has_builtin(__builtin_amdgcn_fdot2)
  return __builtin_amdgcn_fdot2(ua.h, ub.h, acc, false);
#else
  return acc + (float)ua.h.x * (float)ub.h.x + (float)ua.h.y * (float)ub.h.y;
#endif
}

__device__ __forceinline__ int dot4i8(int a, int b, int c) {
#if __has_builtin(__builtin_amdgcn_sdot4)
  return __builtin_amdgcn_sdot4(a, b, c, false);
#else
  int r = c;
  r += (int)(signed char)(a)       * (int)(signed char)(b);
  r += (int)(signed char)(a >> 8)  * (int)(signed char)(b >> 8);
  r += (int)(signed char)(a >> 16) * (int)(signed char)(b >> 16);
  r += (int)(signed char)(a >> 24) * (int)(signed char)(b >> 24);
  return r;
#endif
}

__device__ __forceinline__ float ex2(float x) {
#if __has_builtin(__builtin_amdgcn_exp2f)
  return __builtin_amdgcn_exp2f(x);
#else
  return __exp2f(x);
#endif
}
__device__ __forceinline__ float rcp_(float x) {
#if __has_builtin(__builtin_amdgcn_rcpf)
  return __builtin_amdgcn_rcpf(x);
#else
  return 1.f / x;
#endif
}

template <int C> __device__ __forceinline__ int dppi(int x) {
  return __builtin_amdgcn_mov_dpp(x, C, 0xf, 0xf, false);
}
template <int C> __device__ __forceinline__ float dppf(float x) {
  return __int_as_float(__builtin_amdgcn_mov_dpp(__float_as_int(x), C, 0xf, 0xf, false));
}
// quad_perm ctrl: xor1=0xB1, xor2=0x4E, bcast lane0..3 = 0x00,0x55,0xAA,0xFF

// fast sigmoid/tanh via v_exp_f32 + v_rcp_f32
__device__ __forceinline__ float fsig(float x) {        // sigmoid(x)
  return rcp_(1.f + ex2(-1.442695041f * x));
}
__device__ __forceinline__ float ftanh(float x) {       // tanh(x)
  return fmaf(2.f, rcp_(1.f + ex2(-2.885390082f * x)), -1.f);
}

// ---------------- Kernel 1: char LSTM (batch 4096, 16 steps, H=128) -------------
__global__ __launch_bounds__(256) void k_char_lstm(
    const int* __restrict__ chars, const int* __restrict__ char_lens,
    const float* __restrict__ char_emb,
    const float* __restrict__ cW_ih, const float* __restrict__ cW_hh,
    const float* __restrict__ cb_ih, const float* __restrict__ cb_hh,
    float* __restrict__ char_final) {
  __shared__ hf emb_s[128 * CED];      // 16 KB
  __shared__ hf h_s[2][8][CHD];        // 4 KB
  __shared__ int chars_s[8 * LCH];
  __shared__ int lens_s[8];

  const int tid = threadIdx.x;
  const int u = tid >> 1, kh = tid & 1;
  const int w0 = blockIdx.x * 8;

  for (int i = tid; i < 128 * CED; i += 256) emb_s[i] = (hf)char_emb[i];
  for (int i = tid; i < 8 * LCH; i += 256) chars_s[i] = chars[w0 * LCH + i];
  if (tid < 8) lens_s[tid] = char_lens[w0 + tid];
  {
    hf* hz = &h_s[0][0][0];
    for (int i = tid; i < 8 * CHD; i += 256) hz[i] = (hf)0.f;
  }

  int wih[4][16];
  int whh[4][32];
  float bq[4];
#pragma unroll
  for (int q = 0; q < 4; ++q) {
    const int r = q * CHD + u;
    const float* pi = cW_ih + r * CED + 32 * kh;
#pragma unroll
    for (int j = 0; j < 16; ++j) { PK2 v; v.h.x = (hf)pi[2*j]; v.h.y = (hf)pi[2*j+1]; wih[q][j] = v.i; }
    const float* ph = cW_hh + r * CHD + 64 * kh;
#pragma unroll
    for (int j = 0; j < 32; ++j) { PK2 v; v.h.x = (hf)ph[2*j]; v.h.y = (hf)ph[2*j+1]; whh[q][j] = v.i; }
    bq[q] = cb_ih[r] + cb_hh[r];
  }
  float c[8];
#pragma unroll
  for (int w = 0; w < 8; ++w) c[w] = 0.f;
  __syncthreads();

  for (int t = 0; t < LCH; ++t) {
    const int cur = t & 1, nxt = cur ^ 1;
#pragma unroll
    for (int w = 0; w < 8; ++w) {
      const int cidx = chars_s[w * LCH + t];
      const int4* xr4 = (const int4*)(emb_s + cidx * CED + 32 * kh);
      const int4* hr4 = (const int4*)(&h_s[cur][w][64 * kh]);
      int xi[16], hi[32];
#pragma unroll
      for (int j = 0; j < 4; ++j) *(int4*)(xi + 4 * j) = xr4[j];
#pragma unroll
      for (int j = 0; j < 8; ++j) *(int4*)(hi + 4 * j) = hr4[j];
      float a0 = 0.f, a1 = 0.f, a2 = 0.f, a3 = 0.f;
#pragma unroll
      for (int j = 0; j < 16; ++j) {
        a0 = dot2i(wih[0][j], xi[j], a0); a1 = dot2i(wih[1][j], xi[j], a1);
        a2 = dot2i(wih[2][j], xi[j], a2); a3 = dot2i(wih[3][j], xi[j], a3);
      }
#pragma unroll
      for (int j = 0; j < 32; ++j) {
        a0 = dot2i(whh[0][j], hi[j], a0); a1 = dot2i(whh[1][j], hi[j], a1);
        a2 = dot2i(whh[2][j], hi[j], a2); a3 = dot2i(whh[3][j], hi[j], a3);
      }
      a0 += dppf<0xB1>(a0); a1 += dppf<0xB1>(a1);
      a2 += dppf<0xB1>(a2); a3 += dppf<0xB1>(a3);
      const float ig = fsig(a0 + bq[0]);
      const float fg = fsig(a1 + bq[1]);
      const float gg = ftanh(a2 + bq[2]);
      const float og = fsig(a3 + bq[3]);
      c[w] = fmaf(fg, c[w], ig * gg);
      const float hn = og * ftanh(c[w]);
      if (kh == 0) {
        h_s[nxt][w][u] = (hf)hn;
        if (t == lens_s[w] - 1) char_final[(w0 + w) * CHD + u] = hn;
      }
    }
    __syncthreads();
  }
}

// ---------------- Kernel 2: word-LSTM input part (parallel) ----------------------
// slot(tid): gate = 256*(tid&3) + (tid>>2).  Stores em(gate-type) * preact so the
// serial kernel's sigmoid argument is a single fmaf.
__global__ __launch_bounds__(1024) void k_wxp(
    const int* __restrict__ sent, const float* __restrict__ word_emb,
    const float* __restrict__ char_final,
    const float* __restrict__ wW_ih, const float* __restrict__ wb_ih,
    const float* __restrict__ wb_hh, float* __restrict__ xp) {
  __shared__ float comb[16][WED + CHD];
  const int tid = threadIdx.x;
  const int s0 = blockIdx.x * 16;
  for (int i = tid; i < 16 * WED; i += 1024) {
    const int w = i / WED, k = i % WED;
    comb[w][k] = word_emb[(long)sent[s0 + w] * WED + k];
  }
  for (int i = tid; i < 16 * CHD; i += 1024) {
    const int w = i / CHD, k = i % CHD;
    comb[w][WED + k] = char_final[(s0 + w) * CHD + k];
  }
  __syncthreads();

  const int gate = 256 * (tid & 3) + (tid >> 2);
  const float escale = ((tid & 3) == 2) ? -2.885390082f : -1.442695041f;
  const float bias = wb_ih[gate] + wb_hh[gate];
  float acc[16];
#pragma unroll
  for (int w = 0; w < 16; ++w) acc[w] = bias;
  const float* wrow = wW_ih + gate * (WED + CHD);
  for (int kc = 0; kc < WED + CHD; kc += 64) {
    const float4* wr4 = (const float4*)(wrow + kc);
    float4 wv[16];
#pragma unroll
    for (int i = 0; i < 16; ++i) wv[i] = wr4[i];
#pragma unroll
    for (int w = 0; w < 16; ++w) {
      const float4* cr = (const float4*)&comb[w][kc];
      float a = 0.f;
#pragma unroll
      for (int i = 0; i < 16; ++i) {
        float4 cv = cr[i];
        a += wv[i].x * cv.x + wv[i].y * cv.y + wv[i].z * cv.z + wv[i].w * cv.w;
      }
      acc[w] += a;
    }
  }
#pragma unroll
  for (int w = 0; w < 16; ++w) xp[(long)(s0 + w) * 1024 + tid] = escale * acc[w];
}

// ---------------- Kernel 3: word LSTM recurrence (serial, 1 block) ---------------
// 1024 threads (16 waves, 4/SIMD). Quad p owns unit p; lane l = gate-type l over
// k-slice [64l,64l+64). REGISTER DIET vs round 4: xp prefetch depth 2 (was 8),
// em folded into xp and dq (edq), minimal temporaries -> peak ~112 regs, aiming
// for pure arch-VGPR allocation (no AGPR split / accvgpr moves).
__global__ __launch_bounds__(1024) void k_word_lstm(
    const float* __restrict__ wW_hh, const float* __restrict__ xp,
    float* __restrict__ h_all) {
  __shared__ int hq[2][WHD / 4];  // int8-packed h, 256 B per buffer
  const int t = threadIdx.x;
  const int p = t >> 2, l = t & 3;

  float m0, m1, m2, m3;
  int wq0[16], wq1[16], wq2[16], wq3[16];

#define ROWMAX(mdst, row) do {                                                  \
    const float4* wr_ = (const float4*)(wW_hh + (long)(row) * WHD + 64 * l);    \
    float m_ = 0.f;                                                             \
    _Pragma("unroll")                                                           \
    for (int j = 0; j < 16; ++j) {                                              \
      float4 v = wr_[j];                                                        \
      m_ = fmaxf(m_, fmaxf(fmaxf(fabsf(v.x), fabsf(v.y)),                       \
                           fmaxf(fabsf(v.z), fabsf(v.w))));                     \
    }                                                                           \
    m_ = fmaxf(m_, dppf<0xB1>(m_)); m_ = fmaxf(m_, dppf<0x4E>(m_));             \
    (mdst) = m_;                                                                \
  } while (0)

  ROWMAX(m0, 0 * WHD + p); ROWMAX(m1, 1 * WHD + p);
  ROWMAX(m2, 2 * WHD + p); ROWMAX(m3, 3 * WHD + p);
#undef ROWMAX

#define QROW(dst, row, mreg) do {                                               \
    const float4* wr_ = (const float4*)(wW_hh + (long)(row) * WHD + 64 * l);    \
    const float r_ = ((mreg) > 0.f) ? 127.f / (mreg) : 0.f;                     \
    _Pragma("unroll")                                                           \
    for (int j = 0; j < 16; ++j) {                                              \
      float4 v = wr_[j];                                                        \
      const int b0 = (int)rintf(v.x * r_) & 255;                                \
      const int b1 = (int)rintf(v.y * r_) & 255;                                \
      const int b2 = (int)rintf(v.z * r_) & 255;                                \
      const int b3 = (int)rintf(v.w * r_) & 255;                                \
      dst[j] = b0 | (b1 << 8) | (b2 << 16) | (b3 << 24);                        \
    }                                                                           \
  } while (0)

  QROW(wq0, 0 * WHD + p, m0); QROW(wq1, 1 * WHD + p, m1);
  QROW(wq2, 2 * WHD + p, m2); QROW(wq3, 3 * WHD + p, m3);
#undef QROW

  // own-gate dequant scale with em folded in: arg = oi*edq + xp_pre
  const float ma = (l & 1) ? m1 : m0;
  const float mb = (l & 1) ? m3 : m2;
  const float msel = (l & 2) ? mb : ma;
  const float em = (l == 2) ? -2.885390082f : -1.442695041f;
  const float edq = em * msel * (1.f / (127.f * 127.f));
  const float s_ = (l == 2) ? 2.f : 1.f;
  const float d_ = (l == 2) ? -1.f : 0.f;

  if (t < 128) ((int*)hq)[t] = 0;
  float c = 0.f;
  __syncthreads();

  const float* xq = xp + t;                       // value for step T at xq[T*1024]
  const int4* hb = ((const int4*)hq) + 4 * l;     // l's k-slice, buffers at +0/+16
  signed char* hw = ((signed char*)hq) + p;       // quantized h write slot

#define D4(j, W) do {                                                           \
    a0 = dot4i8(wq0[j], (W), a0); a1 = dot4i8(wq1[j], (W), a1);                 \
    a2 = dot4i8(wq2[j], (W), a2); a3 = dot4i8(wq3[j], (W), a3);                 \
  } while (0)

#define STEP(T, XV, CUR) do {                                                   \
    const int4 h0 = hb[(CUR) * 16 + 0], h1 = hb[(CUR) * 16 + 1],                \
               h2 = hb[(CUR) * 16 + 2], h3 = hb[(CUR) * 16 + 3];                \
    int a0 = 0, a1 = 0, a2 = 0, a3 = 0;                                         \
    D4(0, h0.x);  D4(1, h0.y);  D4(2, h0.z);  D4(3, h0.w);                      \
    D4(4, h1.x);  D4(5, h1.y);  D4(6, h1.z);  D4(7, h1.w);                      \
    D4(8, h2.x);  D4(9, h2.y);  D4(10, h2.z); D4(11, h2.w);                     \
    D4(12, h3.x); D4(13, h3.y); D4(14, h3.z); D4(15, h3.w);                     \
    int r0 = (l & 1) ? a1 : a0, g0 = (l & 1) ? a0 : a1;                         \
    int r1 = (l & 1) ? a3 : a2, g1 = (l & 1) ? a2 : a3;                         \
    r0 += dppi<0xB1>(g0); r1 += dppi<0xB1>(g1);                                 \
    int oi = (l & 2) ? r1 : r0, g2 = (l & 2) ? r0 : r1;                         \
    oi += dppi<0x4E>(g2);                                                       \
    const float arg = fmaf((float)oi, edq, (XV));                               \
    const float act = fmaf(s_, rcp_(1.f + ex2(arg)), d_);                       \
    const float i_ = dppf<0x00>(act), f_ = dppf<0x55>(act);                     \
    const float g_ = dppf<0xAA>(act), o_ = dppf<0xFF>(act);                     \
    c = fmaf(f_, c, i_ * g_);                                                   \
    const float tc = fmaf(2.f, rcp_(1.f + ex2(-2.885390082f * c)), -1.f);       \
    const float hn = o_ * tc;                                                   \
    if (l == 0) hw[((CUR) ^ 1) * 256] = (signed char)(int)rintf(hn * 127.f);    \
    if (l == 1) h_all[(long)(T) * WHD + p] = hn;                                \
    asm volatile("s_waitcnt lgkmcnt(0)\n\ts_barrier" ::: "memory");             \
  } while (0)

  float xa = xq[0];
  float xb = xq[1024];
  xq += 2048;
  for (int t0 = 0; t0 < S_LEN; t0 += 2) {
    const float xn0 = xq[0];        // steps t0+2, t0+3 (xp padded by 2 rows)
    const float xn1 = xq[1024];
    xq += 2048;
    STEP(t0 + 0, xa, 0);
    STEP(t0 + 1, xb, 1);
    xa = xn0; xb = xn1;
  }
#undef STEP
#undef D4
}

// ---------------- Kernel 4: tag projection + log_softmax ------------------------
__global__ __launch_bounds__(64) void k_tag(
    const float* __restrict__ h_all, const float* __restrict__ tagW,
    const float* __restrict__ tagb, float* __restrict__ out) {
  __shared__ float hrow[WHD];
  const int s = blockIdx.x, t = threadIdx.x;
  for (int i = t; i < WHD; i += 64) hrow[i] = h_all[(long)s * WHD + i];
  __syncthreads();
  const float4* wr = (const float4*)(tagW + t * WHD);
  const float4* hr = (const float4*)hrow;
  float a = tagb[t];
#pragma unroll
  for (int i = 0; i < 64; ++i) {
    float4 w4 = wr[i], h4 = hr[i];
    a += w4.x * h4.x + w4.y * h4.y + w4.z * h4.z + w4.w * h4.w;
  }
  float m = a;
#pragma unroll
  for (int d = 1; d < 64; d <<= 1) m = fmaxf(m, __shfl_xor(m, d));
  const float e = __expf(a - m);
  float sum = e;
#pragma unroll
  for (int d = 1; d < 64; d <<= 1) sum += __shfl_xor(sum, d);
  out[(long)s * TAGV + t] = (a - m) - logf(sum);
}

extern "C" void kernel_launch(void* const* d_in, const int* in_sizes, int n_in,
                              void* d_out, int out_size, void* d_ws, size_t ws_size,
                              hipStream_t stream) {
  const int* sent       = (const int*)d_in[0];
  const int* chars      = (const int*)d_in[1];
  const int* char_lens  = (const int*)d_in[2];
  const float* char_emb = (const float*)d_in[3];
  const float* word_emb = (const float*)d_in[4];
  const float* cW_ih    = (const float*)d_in[5];
  const float* cW_hh    = (const float*)d_in[6];
  const float* cb_ih    = (const float*)d_in[7];
  const float* cb_hh    = (const float*)d_in[8];
  const float* wW_ih    = (const float*)d_in[9];
  const float* wW_hh    = (const float*)d_in[10];
  const float* wb_ih    = (const float*)d_in[11];
  const float* wb_hh    = (const float*)d_in[12];
  const float* tagW     = (const float*)d_in[13];
  const float* tagb     = (const float*)d_in[14];
  float* out = (float*)d_out;

  char* ws = (char*)d_ws;
  float* char_final = (float*)ws;                          // 4096*128*4  = 2 MB
  float* xp         = (float*)(ws + ((size_t)2 << 20));    // (4096+2)*1024*4 ≈ 16 MB (+2 pad rows for prefetch)
  float* h_all      = (float*)(ws + ((size_t)20 << 20));   // 4096*256*4  = 4 MB

  hipLaunchKernelGGL(k_char_lstm, dim3(512), dim3(256), 0, stream,
                     chars, char_lens, char_emb, cW_ih, cW_hh, cb_ih, cb_hh, char_final);
  hipLaunchKernelGGL(k_wxp, dim3(256), dim3(1024), 0, stream,
                     sent, word_emb, char_final, wW_ih, wb_ih, wb_hh, xp);
  hipLaunchKernelGGL(k_word_lstm, dim3(1), dim3(1024), 0, stream, wW_hh, xp, h_all);
  hipLaunchKernelGGL(k_tag, dim3(4096), dim3(64), 0, stream, h_all, tagW, tagb, out);
}